// Round 3
// baseline (448.821 us; speedup 1.0000x reference)
//
#include <hip/hip_runtime.h>

// Problem constants (fixed by the reference).
#define N_NODES   50000
#define N_EDGES   400000
#define IN_DIM    128
#define OUT_DIM   32
#define EDGE_DIM  64
#define HEADS     8
#define HC        256          // HEADS * OUT_DIM
#define N_REL     512
#define NEG_SLOPE 0.2f
#define NB_SCAN   196          // ceil(50000/256)
#define KT        64           // GEMM K-tile

// ---------------------------------------------------------------------------
// Register-tiled fp32 GEMM: C[M, 256] = A[M, K] @ W[K, 256] (+ bias)
// Only a 64-column tile per block: block tile 64x64, 16x16 threads, 4x4 regs.
// A row stride == K; W row stride == 256; C row stride == 256.
// ---------------------------------------------------------------------------
template<int K>
__global__ __launch_bounds__(256) void k_gemm(
        const float* __restrict__ A, const float* __restrict__ W,
        const float* __restrict__ bias, float* __restrict__ C, int M) {
    __shared__ float As[64][KT + 4];   // pad -> 2-way banking (free)
    __shared__ float Ws[KT][64];
    const int bid = blockIdx.x;
    const int mt = bid >> 2, ct = bid & 3;
    const int n0 = mt * 64;
    const int c0 = ct * 64;
    const int t  = threadIdx.x;
    const int tx = t & 15, ty = t >> 4;

    float acc[4][4];
    if (bias) {
        const float4 b4 = *(const float4*)(bias + c0 + tx * 4);
#pragma unroll
        for (int mi = 0; mi < 4; ++mi) {
            acc[mi][0] = b4.x; acc[mi][1] = b4.y;
            acc[mi][2] = b4.z; acc[mi][3] = b4.w;
        }
    } else {
#pragma unroll
        for (int mi = 0; mi < 4; ++mi)
#pragma unroll
            for (int ci = 0; ci < 4; ++ci) acc[mi][ci] = 0.f;
    }

    for (int kt = 0; kt < K; kt += KT) {
        // Stage A tile: 64 rows x KT cols (coalesced float4 reads).
#pragma unroll
        for (int i = t * 4; i < 64 * KT; i += 1024) {
            const int node = i >> 6;
            const int kk   = i & 63;
            const int row  = n0 + node;
            float4 v = make_float4(0.f, 0.f, 0.f, 0.f);
            if (row < M) v = *(const float4*)(A + (size_t)row * K + kt + kk);
            *(float4*)&As[node][kk] = v;
        }
        // Stage W tile: KT rows x 64 cols.
#pragma unroll
        for (int i = t * 4; i < KT * 64; i += 1024) {
            const int kk = i >> 6;
            const int c  = i & 63;
            *(float4*)&Ws[kk][c] =
                *(const float4*)(W + (size_t)(kt + kk) * HC + c0 + c);
        }
        __syncthreads();

#pragma unroll
        for (int k = 0; k < KT; k += 4) {
            const float4 a0 = *(const float4*)&As[ty * 4 + 0][k];
            const float4 a1 = *(const float4*)&As[ty * 4 + 1][k];
            const float4 a2 = *(const float4*)&As[ty * 4 + 2][k];
            const float4 a3 = *(const float4*)&As[ty * 4 + 3][k];
            const float4 w0 = *(const float4*)&Ws[k + 0][tx * 4];
            const float4 w1 = *(const float4*)&Ws[k + 1][tx * 4];
            const float4 w2 = *(const float4*)&Ws[k + 2][tx * 4];
            const float4 w3 = *(const float4*)&Ws[k + 3][tx * 4];
#define GSTEP(mi, AV)                                                          \
            acc[mi][0] = fmaf(AV.x, w0.x, fmaf(AV.y, w1.x,                     \
                         fmaf(AV.z, w2.x, fmaf(AV.w, w3.x, acc[mi][0]))));     \
            acc[mi][1] = fmaf(AV.x, w0.y, fmaf(AV.y, w1.y,                     \
                         fmaf(AV.z, w2.y, fmaf(AV.w, w3.y, acc[mi][1]))));     \
            acc[mi][2] = fmaf(AV.x, w0.z, fmaf(AV.y, w1.z,                     \
                         fmaf(AV.z, w2.z, fmaf(AV.w, w3.z, acc[mi][2]))));     \
            acc[mi][3] = fmaf(AV.x, w0.w, fmaf(AV.y, w1.w,                     \
                         fmaf(AV.z, w2.w, fmaf(AV.w, w3.w, acc[mi][3]))))
            GSTEP(0, a0); GSTEP(1, a1); GSTEP(2, a2); GSTEP(3, a3);
#undef GSTEP
        }
        __syncthreads();
    }

#pragma unroll
    for (int mi = 0; mi < 4; ++mi) {
        const int row = n0 + ty * 4 + mi;
        if (row < M) {
            float4 o;
            o.x = acc[mi][0]; o.y = acc[mi][1];
            o.z = acc[mi][2]; o.w = acc[mi][3];
            *(float4*)(C + (size_t)row * HC + c0 + tx * 4) = o;
        }
    }
}

// ---------------------------------------------------------------------------
// Degree histogram (int).
// ---------------------------------------------------------------------------
__global__ void k_deg(const int* __restrict__ dst_arr, int* __restrict__ deg_i) {
    const int e = blockIdx.x * 256 + threadIdx.x;
    if (e < N_EDGES) atomicAdd(&deg_i[dst_arr[e]], 1);
}

// ---------------------------------------------------------------------------
// Block-level inclusive scan of deg -> incl, block sums -> partials.
// ---------------------------------------------------------------------------
__global__ void __launch_bounds__(256) k_scan_a(const int* __restrict__ deg_i,
                                                int* __restrict__ incl,
                                                int* __restrict__ partials) {
    __shared__ int s[256];
    const int i = blockIdx.x * 256 + threadIdx.x;
    const int v = (i < N_NODES) ? deg_i[i] : 0;
    s[threadIdx.x] = v;
    __syncthreads();
#pragma unroll
    for (int o = 1; o < 256; o <<= 1) {
        int t = s[threadIdx.x];
        if (threadIdx.x >= o) t += s[threadIdx.x - o];
        __syncthreads();
        s[threadIdx.x] = t;
        __syncthreads();
    }
    if (i < N_NODES) incl[i] = s[threadIdx.x];
    if (threadIdx.x == 255) partials[blockIdx.x] = s[255];
}

// Exclusive scan of the NB_SCAN block sums (in place).
__global__ void __launch_bounds__(256) k_scan_b(int* __restrict__ partials) {
    __shared__ int s[256];
    const int v = (threadIdx.x < NB_SCAN) ? partials[threadIdx.x] : 0;
    s[threadIdx.x] = v;
    __syncthreads();
#pragma unroll
    for (int o = 1; o < 256; o <<= 1) {
        int t = s[threadIdx.x];
        if (threadIdx.x >= o) t += s[threadIdx.x - o];
        __syncthreads();
        s[threadIdx.x] = t;
        __syncthreads();
    }
    if (threadIdx.x < NB_SCAN) partials[threadIdx.x] = s[threadIdx.x] - v;
}

// row_ptr[i] = exclusive global scan; row_ptr[N] = E.
__global__ void __launch_bounds__(256) k_scan_c(const int* __restrict__ incl,
                                                const int* __restrict__ deg_i,
                                                const int* __restrict__ partials,
                                                int* __restrict__ row_ptr) {
    const int i = blockIdx.x * 256 + threadIdx.x;
    if (i < N_NODES) row_ptr[i] = incl[i] - deg_i[i] + partials[blockIdx.x];
    if (i == 0) row_ptr[N_NODES] = N_EDGES;
}

// ---------------------------------------------------------------------------
// Scatter (src, rel) into CSR slots.
// ---------------------------------------------------------------------------
__global__ void k_fill(const int* __restrict__ src_arr,
                       const int* __restrict__ dst_arr,
                       const int* __restrict__ rel_idx,
                       const int* __restrict__ row_ptr,
                       int* __restrict__ cursor,
                       int2* __restrict__ csr) {
    const int e = blockIdx.x * 256 + threadIdx.x;
    if (e >= N_EDGES) return;
    const int d = dst_arr[e];
    const int pos = row_ptr[d] + atomicAdd(&cursor[d], 1);
    csr[pos] = make_int2(src_arr[e], rel_idx[e]);
}

// ---------------------------------------------------------------------------
// self_attr[n, :] = mean of relations[rel] over incoming edges (CSR walk).
// One wave per node; lane = channel.
// ---------------------------------------------------------------------------
__global__ void __launch_bounds__(256) k_selfattr(
        const int* __restrict__ row_ptr, const int2* __restrict__ csr,
        const float* __restrict__ relations, float* __restrict__ self_attr) {
    const int n = (blockIdx.x * 256 + threadIdx.x) >> 6;
    if (n >= N_NODES) return;
    const int lane = threadIdx.x & 63;
    const int beg = row_ptr[n], end = row_ptr[n + 1];
    float a = 0.f;
    for (int i = beg; i < end; ++i) {
        const int r = csr[i].y;
        a += relations[r * EDGE_DIM + lane];
    }
    const float dg = (float)max(end - beg, 1);
    self_attr[n * EDGE_DIM + lane] = a / dg;
}

// ---------------------------------------------------------------------------
// Aggregation: one wave per destination node. Register accumulation, no
// atomics. lane -> (h = lane>>3, q = lane&7), float4 chunk per lane.
// Fuses softmax normalization, head mean, and bias.
// ---------------------------------------------------------------------------
__global__ void __launch_bounds__(256) k_agg(
        const int* __restrict__ row_ptr, const int2* __restrict__ csr,
        const float* __restrict__ x_l, const float* __restrict__ x_r,
        const float* __restrict__ rel_emb, const float* __restrict__ self_emb,
        const float* __restrict__ att, const float* __restrict__ bias,
        float* __restrict__ out) {
    const int n = (blockIdx.x * 256 + threadIdx.x) >> 6;
    if (n >= N_NODES) return;
    const int lane = threadIdx.x & 63;
    const int q = lane & 7;
    const int off = (lane >> 3) * OUT_DIM + q * 4;

    const float4 at = *(const float4*)(att + off);
    const float4 xr = *(const float4*)(x_r + (size_t)n * HC + off);

    // Self-loop term.
    const float4 xls = *(const float4*)(x_l + (size_t)n * HC + off);
    const float4 se  = *(const float4*)(self_emb + (size_t)n * HC + off);
    float m0 = xls.x + xr.x + se.x; m0 = m0 >= 0.f ? m0 : NEG_SLOPE * m0;
    float m1 = xls.y + xr.y + se.y; m1 = m1 >= 0.f ? m1 : NEG_SLOPE * m1;
    float m2 = xls.z + xr.z + se.z; m2 = m2 >= 0.f ? m2 : NEG_SLOPE * m2;
    float m3 = xls.w + xr.w + se.w; m3 = m3 >= 0.f ? m3 : NEG_SLOPE * m3;
    float p = at.x * m0 + at.y * m1 + at.z * m2 + at.w * m3;
    p += __shfl_xor(p, 1);
    p += __shfl_xor(p, 2);
    p += __shfl_xor(p, 4);
    float ex = __expf(p);
    float den = ex;
    float4 acc;
    acc.x = ex * xls.x; acc.y = ex * xls.y; acc.z = ex * xls.z; acc.w = ex * xls.w;

    const int beg = row_ptr[n], end = row_ptr[n + 1];
    for (int i = beg; i < end; ++i) {
        const int2 sr = csr[i];
        const float4 xl = *(const float4*)(x_l + (size_t)sr.x * HC + off);
        const float4 ev = *(const float4*)(rel_emb + (size_t)sr.y * HC + off);
        float a0 = xl.x + xr.x + ev.x; a0 = a0 >= 0.f ? a0 : NEG_SLOPE * a0;
        float a1 = xl.y + xr.y + ev.y; a1 = a1 >= 0.f ? a1 : NEG_SLOPE * a1;
        float a2 = xl.z + xr.z + ev.z; a2 = a2 >= 0.f ? a2 : NEG_SLOPE * a2;
        float a3 = xl.w + xr.w + ev.w; a3 = a3 >= 0.f ? a3 : NEG_SLOPE * a3;
        float pp = at.x * a0 + at.y * a1 + at.z * a2 + at.w * a3;
        pp += __shfl_xor(pp, 1);
        pp += __shfl_xor(pp, 2);
        pp += __shfl_xor(pp, 4);
        const float e2 = __expf(pp);
        den += e2;
        acc.x = fmaf(e2, xl.x, acc.x);
        acc.y = fmaf(e2, xl.y, acc.y);
        acc.z = fmaf(e2, xl.z, acc.z);
        acc.w = fmaf(e2, xl.w, acc.w);
    }

    // Normalize per head, then mean over heads (reduce across lane bits 3..5).
    const float inv = 1.f / den;
    float4 v;
    v.x = acc.x * inv; v.y = acc.y * inv; v.z = acc.z * inv; v.w = acc.w * inv;
    v.x += __shfl_xor(v.x, 8);  v.y += __shfl_xor(v.y, 8);
    v.z += __shfl_xor(v.z, 8);  v.w += __shfl_xor(v.w, 8);
    v.x += __shfl_xor(v.x, 16); v.y += __shfl_xor(v.y, 16);
    v.z += __shfl_xor(v.z, 16); v.w += __shfl_xor(v.w, 16);
    v.x += __shfl_xor(v.x, 32); v.y += __shfl_xor(v.y, 32);
    v.z += __shfl_xor(v.z, 32); v.w += __shfl_xor(v.w, 32);
    if (lane < 8) {
        const float4 bs = *(const float4*)(bias + q * 4);
        float4 o;
        o.x = v.x * 0.125f + bs.x;
        o.y = v.y * 0.125f + bs.y;
        o.z = v.z * 0.125f + bs.z;
        o.w = v.w * 0.125f + bs.w;
        *(float4*)(out + (size_t)n * OUT_DIM + q * 4) = o;
    }
}

__global__ void k_copy_rel(const float* __restrict__ relations,
                           float* __restrict__ out_tail) {
    const int i = blockIdx.x * 256 + threadIdx.x;
    if (i < N_REL * EDGE_DIM) out_tail[i] = relations[i];
}

// ---------------------------------------------------------------------------
extern "C" void kernel_launch(void* const* d_in, const int* in_sizes, int n_in,
                              void* d_out, int out_size, void* d_ws, size_t ws_size,
                              hipStream_t stream) {
    const float* x         = (const float*)d_in[0];
    const int*   edge_idx  = (const int*)d_in[1];
    const float* relations = (const float*)d_in[2];
    const int*   rel_idx   = (const int*)d_in[3];
    const float* W_l       = (const float*)d_in[4];
    const float* b_l       = (const float*)d_in[5];
    const float* W_r       = (const float*)d_in[6];
    const float* b_r       = (const float*)d_in[7];
    const float* W_e       = (const float*)d_in[8];
    const float* att       = (const float*)d_in[9];
    const float* bias      = (const float*)d_in[10];

    const int* src_arr = edge_idx;            // edge_index[0, :]
    const int* dst_arr = edge_idx + N_EDGES;  // edge_index[1, :]

    float* out      = (float*)d_out;                 // [N, 32]
    float* out_tail = out + N_NODES * OUT_DIM;       // relations copy

    // Workspace layout (16B-aligned chunks; all counts multiple of 4).
    float* ws        = (float*)d_ws;
    float* x_l       = ws;                                    // 12.8M f
    float* x_r       = x_l + (size_t)N_NODES * HC;            // 12.8M f
    float* self_emb  = x_r + (size_t)N_NODES * HC;            // 12.8M f
    float* rel_emb   = self_emb + (size_t)N_NODES * HC;       // 131072 f
    float* self_attr = rel_emb + (size_t)N_REL * HC;          // 3.2M f
    int*   ibase     = (int*)(self_attr + (size_t)N_NODES * EDGE_DIM);
    int2*  csr       = (int2*)ibase;                          // 400000 int2
    int*   row_ptr   = ibase + 2 * N_EDGES;                   // 50001 (+pad 3)
    int*   incl      = row_ptr + N_NODES + 4;                 // 50000
    int*   deg_i     = incl + N_NODES;                        // 50000 \ zeroed
    int*   cursor    = deg_i + N_NODES;                       // 50000 / together
    int*   partials  = cursor + N_NODES;                      // 256

    hipMemsetAsync(deg_i, 0, 2 * N_NODES * sizeof(int), stream);

    // CSR build.
    k_deg<<<(N_EDGES + 255) / 256, 256, 0, stream>>>(dst_arr, deg_i);
    k_scan_a<<<NB_SCAN, 256, 0, stream>>>(deg_i, incl, partials);
    k_scan_b<<<1, 256, 0, stream>>>(partials);
    k_scan_c<<<NB_SCAN, 256, 0, stream>>>(incl, deg_i, partials, row_ptr);
    k_fill<<<(N_EDGES + 255) / 256, 256, 0, stream>>>(
        src_arr, dst_arr, rel_idx, row_ptr, cursor, csr);

    // Projections (register-tiled GEMMs).
    const int mt_nodes = (N_NODES + 63) / 64;   // 782
    const int mt_rel   = (N_REL + 63) / 64;     // 8
    k_gemm<128><<<mt_nodes * 4, 256, 0, stream>>>(x, W_l, b_l, x_l, N_NODES);
    k_gemm<128><<<mt_nodes * 4, 256, 0, stream>>>(x, W_r, b_r, x_r, N_NODES);
    k_gemm<64><<<mt_rel * 4, 256, 0, stream>>>(relations, W_e, nullptr,
                                               rel_emb, N_REL);

    k_selfattr<<<(N_NODES * 64 + 255) / 256, 256, 0, stream>>>(
        row_ptr, csr, relations, self_attr);
    k_gemm<64><<<mt_nodes * 4, 256, 0, stream>>>(self_attr, W_e, nullptr,
                                                 self_emb, N_NODES);

    // Gather-aggregate + epilogue.
    k_agg<<<(N_NODES * 64 + 255) / 256, 256, 0, stream>>>(
        row_ptr, csr, x_l, x_r, rel_emb, self_emb, att, bias, out);

    k_copy_rel<<<(N_REL * EDGE_DIM + 255) / 256, 256, 0, stream>>>(
        relations, out_tail);
}

// Round 5
// 400.784 us; speedup vs baseline: 1.1199x; 1.1199x over previous
//
#include <hip/hip_runtime.h>

// Problem constants (fixed by the reference).
#define N_NODES   50000
#define N_EDGES   400000
#define IN_DIM    128
#define OUT_DIM   32
#define EDGE_DIM  64
#define HEADS     8
#define HC        256          // HEADS * OUT_DIM
#define N_REL     512
#define NEG_SLOPE 0.2f
#define NB_SCAN   196          // ceil(50000/256)
#define KT        64           // GEMM K-tile

// ---------------------------------------------------------------------------
// Register-tiled fp32 GEMM, optionally dual-weight (shared A tile):
//   C1[M, 256] = A[M, K] @ W1[K, 256] (+ b1)
//   C2[M, 256] = A[M, K] @ W2[K, 256] (+ b2)     (DUAL only)
// Block tile 64 rows x 64 cols, 16x16 threads, 4x4 regs per output.
// K-tiles are software-pipelined through registers (stage, sync, prefetch,
// compute, sync). __launch_bounds__(256,3) keeps VGPR <= ~168 so 3 blocks/CU.
// ---------------------------------------------------------------------------
template<int K, bool DUAL>
__global__ __launch_bounds__(256, 3) void k_gemm(
        const float* __restrict__ A,
        const float* __restrict__ W1, const float* __restrict__ b1,
        const float* __restrict__ W2, const float* __restrict__ b2,
        float* __restrict__ C1, float* __restrict__ C2, int M) {
    __shared__ float As[64][KT + 4];            // pad -> conflict-free
    __shared__ float W1s[KT][64];
    __shared__ float W2s[DUAL ? KT : 1][64];
    const int bid = blockIdx.x;
    const int mt = bid >> 2, ct = bid & 3;
    const int n0 = mt * 64;
    const int c0 = ct * 64;
    const int t  = threadIdx.x;
    const int tx = t & 15, ty = t >> 4;

    float acc1[4][4], acc2[4][4];
    {
        float4 b14 = make_float4(0.f, 0.f, 0.f, 0.f);
        float4 b24 = make_float4(0.f, 0.f, 0.f, 0.f);
        if (b1) b14 = *(const float4*)(b1 + c0 + tx * 4);
        if (DUAL && b2) b24 = *(const float4*)(b2 + c0 + tx * 4);
#pragma unroll
        for (int mi = 0; mi < 4; ++mi) {
            acc1[mi][0] = b14.x; acc1[mi][1] = b14.y;
            acc1[mi][2] = b14.z; acc1[mi][3] = b14.w;
            acc2[mi][0] = b24.x; acc2[mi][1] = b24.y;
            acc2[mi][2] = b24.z; acc2[mi][3] = b24.w;
        }
    }

    // Staging map: 4 float4 per matrix per thread.
    // flat float4 index i = t + j*256 (j=0..3): row = i>>4, col4 = (i&15)*4.
    float4 ra[4], rw1[4], rw2[4];
#pragma unroll
    for (int j = 0; j < 4; ++j) {
        const int i   = t + j * 256;
        const int row = i >> 4;
        const int cc  = (i & 15) * 4;
        ra[j] = make_float4(0.f, 0.f, 0.f, 0.f);
        if (n0 + row < M)
            ra[j] = *(const float4*)(A + (size_t)(n0 + row) * K + cc);
        rw1[j] = *(const float4*)(W1 + (size_t)row * HC + c0 + cc);
        if (DUAL)
            rw2[j] = *(const float4*)(W2 + (size_t)row * HC + c0 + cc);
    }

    for (int kt = 0; kt < K; kt += KT) {
        // Write staged registers to LDS.
#pragma unroll
        for (int j = 0; j < 4; ++j) {
            const int i   = t + j * 256;
            const int row = i >> 4;
            const int cc  = (i & 15) * 4;
            *(float4*)&As[row][cc]  = ra[j];
            *(float4*)&W1s[row][cc] = rw1[j];
            if (DUAL) *(float4*)&W2s[row][cc] = rw2[j];
        }
        __syncthreads();

        // Prefetch next K-tile into registers (hidden under compute).
        if (kt + KT < K) {
#pragma unroll
            for (int j = 0; j < 4; ++j) {
                const int i   = t + j * 256;
                const int row = i >> 4;
                const int cc  = (i & 15) * 4;
                ra[j] = make_float4(0.f, 0.f, 0.f, 0.f);
                if (n0 + row < M)
                    ra[j] = *(const float4*)(A + (size_t)(n0 + row) * K +
                                             kt + KT + cc);
                rw1[j] = *(const float4*)(W1 + (size_t)(kt + KT + row) * HC +
                                          c0 + cc);
                if (DUAL)
                    rw2[j] = *(const float4*)(W2 + (size_t)(kt + KT + row) * HC +
                                              c0 + cc);
            }
        }

#pragma unroll 2
        for (int k = 0; k < KT; k += 4) {
            const float4 a0 = *(const float4*)&As[ty * 4 + 0][k];
            const float4 a1 = *(const float4*)&As[ty * 4 + 1][k];
            const float4 a2 = *(const float4*)&As[ty * 4 + 2][k];
            const float4 a3 = *(const float4*)&As[ty * 4 + 3][k];
            const float4 u0 = *(const float4*)&W1s[k + 0][tx * 4];
            const float4 u1 = *(const float4*)&W1s[k + 1][tx * 4];
            const float4 u2 = *(const float4*)&W1s[k + 2][tx * 4];
            const float4 u3 = *(const float4*)&W1s[k + 3][tx * 4];
#define GSTEP(ACC, mi, AV)                                                     \
            ACC[mi][0] = fmaf(AV.x, u0.x, fmaf(AV.y, u1.x,                     \
                         fmaf(AV.z, u2.x, fmaf(AV.w, u3.x, ACC[mi][0]))));     \
            ACC[mi][1] = fmaf(AV.x, u0.y, fmaf(AV.y, u1.y,                     \
                         fmaf(AV.z, u2.y, fmaf(AV.w, u3.y, ACC[mi][1]))));     \
            ACC[mi][2] = fmaf(AV.x, u0.z, fmaf(AV.y, u1.z,                     \
                         fmaf(AV.z, u2.z, fmaf(AV.w, u3.z, ACC[mi][2]))));     \
            ACC[mi][3] = fmaf(AV.x, u0.w, fmaf(AV.y, u1.w,                     \
                         fmaf(AV.z, u2.w, fmaf(AV.w, u3.w, ACC[mi][3]))))
            GSTEP(acc1, 0, a0); GSTEP(acc1, 1, a1);
            GSTEP(acc1, 2, a2); GSTEP(acc1, 3, a3);
            if (DUAL) {
                const float4 v0 = *(const float4*)&W2s[k + 0][tx * 4];
                const float4 v1 = *(const float4*)&W2s[k + 1][tx * 4];
                const float4 v2 = *(const float4*)&W2s[k + 2][tx * 4];
                const float4 v3 = *(const float4*)&W2s[k + 3][tx * 4];
#define GSTEP2(mi, AV)                                                         \
            acc2[mi][0] = fmaf(AV.x, v0.x, fmaf(AV.y, v1.x,                    \
                          fmaf(AV.z, v2.x, fmaf(AV.w, v3.x, acc2[mi][0]))));   \
            acc2[mi][1] = fmaf(AV.x, v0.y, fmaf(AV.y, v1.y,                    \
                          fmaf(AV.z, v2.y, fmaf(AV.w, v3.y, acc2[mi][1]))));   \
            acc2[mi][2] = fmaf(AV.x, v0.z, fmaf(AV.y, v1.z,                    \
                          fmaf(AV.z, v2.z, fmaf(AV.w, v3.z, acc2[mi][2]))));   \
            acc2[mi][3] = fmaf(AV.x, v0.w, fmaf(AV.y, v1.w,                    \
                          fmaf(AV.z, v2.w, fmaf(AV.w, v3.w, acc2[mi][3]))))
                GSTEP2(0, a0); GSTEP2(1, a1); GSTEP2(2, a2); GSTEP2(3, a3);
#undef GSTEP2
            }
#undef GSTEP
        }
        __syncthreads();
    }

#pragma unroll
    for (int mi = 0; mi < 4; ++mi) {
        const int row = n0 + ty * 4 + mi;
        if (row < M) {
            float4 o1;
            o1.x = acc1[mi][0]; o1.y = acc1[mi][1];
            o1.z = acc1[mi][2]; o1.w = acc1[mi][3];
            *(float4*)(C1 + (size_t)row * HC + c0 + tx * 4) = o1;
            if (DUAL) {
                float4 o2;
                o2.x = acc2[mi][0]; o2.y = acc2[mi][1];
                o2.z = acc2[mi][2]; o2.w = acc2[mi][3];
                *(float4*)(C2 + (size_t)row * HC + c0 + tx * 4) = o2;
            }
        }
    }
}

// ---------------------------------------------------------------------------
// Degree histogram (int).
// ---------------------------------------------------------------------------
__global__ void k_deg(const int* __restrict__ dst_arr, int* __restrict__ deg_i) {
    const int e = blockIdx.x * 256 + threadIdx.x;
    if (e < N_EDGES) atomicAdd(&deg_i[dst_arr[e]], 1);
}

// ---------------------------------------------------------------------------
// Block-level inclusive scan of deg -> incl, block sums -> partials.
// ---------------------------------------------------------------------------
__global__ void __launch_bounds__(256) k_scan_a(const int* __restrict__ deg_i,
                                                int* __restrict__ incl,
                                                int* __restrict__ partials) {
    __shared__ int s[256];
    const int i = blockIdx.x * 256 + threadIdx.x;
    const int v = (i < N_NODES) ? deg_i[i] : 0;
    s[threadIdx.x] = v;
    __syncthreads();
#pragma unroll
    for (int o = 1; o < 256; o <<= 1) {
        int t = s[threadIdx.x];
        if (threadIdx.x >= o) t += s[threadIdx.x - o];
        __syncthreads();
        s[threadIdx.x] = t;
        __syncthreads();
    }
    if (i < N_NODES) incl[i] = s[threadIdx.x];
    if (threadIdx.x == 255) partials[blockIdx.x] = s[255];
}

// Exclusive scan of the NB_SCAN block sums (in place).
__global__ void __launch_bounds__(256) k_scan_b(int* __restrict__ partials) {
    __shared__ int s[256];
    const int v = (threadIdx.x < NB_SCAN) ? partials[threadIdx.x] : 0;
    s[threadIdx.x] = v;
    __syncthreads();
#pragma unroll
    for (int o = 1; o < 256; o <<= 1) {
        int t = s[threadIdx.x];
        if (threadIdx.x >= o) t += s[threadIdx.x - o];
        __syncthreads();
        s[threadIdx.x] = t;
        __syncthreads();
    }
    if (threadIdx.x < NB_SCAN) partials[threadIdx.x] = s[threadIdx.x] - v;
}

// row_ptr[i] = exclusive global scan; row_ptr[N] = E.
__global__ void __launch_bounds__(256) k_scan_c(const int* __restrict__ incl,
                                                const int* __restrict__ deg_i,
                                                const int* __restrict__ partials,
                                                int* __restrict__ row_ptr) {
    const int i = blockIdx.x * 256 + threadIdx.x;
    if (i < N_NODES) row_ptr[i] = incl[i] - deg_i[i] + partials[blockIdx.x];
    if (i == 0) row_ptr[N_NODES] = N_EDGES;
}

// ---------------------------------------------------------------------------
// Scatter (src, rel) into CSR slots.
// ---------------------------------------------------------------------------
__global__ void k_fill(const int* __restrict__ src_arr,
                       const int* __restrict__ dst_arr,
                       const int* __restrict__ rel_idx,
                       const int* __restrict__ row_ptr,
                       int* __restrict__ cursor,
                       int2* __restrict__ csr) {
    const int e = blockIdx.x * 256 + threadIdx.x;
    if (e >= N_EDGES) return;
    const int d = dst_arr[e];
    const int pos = row_ptr[d] + atomicAdd(&cursor[d], 1);
    csr[pos] = make_int2(src_arr[e], rel_idx[e]);
}

// ---------------------------------------------------------------------------
// self_attr[n, :] = mean of relations[rel] over incoming edges (CSR walk).
// One wave per node; lane = channel.
// ---------------------------------------------------------------------------
__global__ void __launch_bounds__(256) k_selfattr(
        const int* __restrict__ row_ptr, const int2* __restrict__ csr,
        const float* __restrict__ relations, float* __restrict__ self_attr) {
    const int n = (blockIdx.x * 256 + threadIdx.x) >> 6;
    if (n >= N_NODES) return;
    const int lane = threadIdx.x & 63;
    const int beg = row_ptr[n], end = row_ptr[n + 1];
    float a = 0.f;
    for (int i = beg; i < end; ++i) {
        const int r = csr[i].y;
        a += relations[r * EDGE_DIM + lane];
    }
    const float dg = (float)max(end - beg, 1);
    self_attr[n * EDGE_DIM + lane] = a / dg;
}

// ---------------------------------------------------------------------------
// Aggregation: one wave per destination node. Register accumulation, no
// atomics. lane -> (h = lane>>3, q = lane&7), float4 chunk per lane.
// Fuses softmax normalization, head mean, and bias.
// ---------------------------------------------------------------------------
__global__ void __launch_bounds__(256) k_agg(
        const int* __restrict__ row_ptr, const int2* __restrict__ csr,
        const float* __restrict__ x_l, const float* __restrict__ x_r,
        const float* __restrict__ rel_emb, const float* __restrict__ self_emb,
        const float* __restrict__ att, const float* __restrict__ bias,
        float* __restrict__ out) {
    const int n = (blockIdx.x * 256 + threadIdx.x) >> 6;
    if (n >= N_NODES) return;
    const int lane = threadIdx.x & 63;
    const int q = lane & 7;
    const int off = (lane >> 3) * OUT_DIM + q * 4;

    const float4 at = *(const float4*)(att + off);
    const float4 xr = *(const float4*)(x_r + (size_t)n * HC + off);

    // Self-loop term.
    const float4 xls = *(const float4*)(x_l + (size_t)n * HC + off);
    const float4 se  = *(const float4*)(self_emb + (size_t)n * HC + off);
    float m0 = xls.x + xr.x + se.x; m0 = m0 >= 0.f ? m0 : NEG_SLOPE * m0;
    float m1 = xls.y + xr.y + se.y; m1 = m1 >= 0.f ? m1 : NEG_SLOPE * m1;
    float m2 = xls.z + xr.z + se.z; m2 = m2 >= 0.f ? m2 : NEG_SLOPE * m2;
    float m3 = xls.w + xr.w + se.w; m3 = m3 >= 0.f ? m3 : NEG_SLOPE * m3;
    float p = at.x * m0 + at.y * m1 + at.z * m2 + at.w * m3;
    p += __shfl_xor(p, 1);
    p += __shfl_xor(p, 2);
    p += __shfl_xor(p, 4);
    float ex = __expf(p);
    float den = ex;
    float4 acc;
    acc.x = ex * xls.x; acc.y = ex * xls.y; acc.z = ex * xls.z; acc.w = ex * xls.w;

    const int beg = row_ptr[n], end = row_ptr[n + 1];
    for (int i = beg; i < end; ++i) {
        const int2 sr = csr[i];
        const float4 xl = *(const float4*)(x_l + (size_t)sr.x * HC + off);
        const float4 ev = *(const float4*)(rel_emb + (size_t)sr.y * HC + off);
        float a0 = xl.x + xr.x + ev.x; a0 = a0 >= 0.f ? a0 : NEG_SLOPE * a0;
        float a1 = xl.y + xr.y + ev.y; a1 = a1 >= 0.f ? a1 : NEG_SLOPE * a1;
        float a2 = xl.z + xr.z + ev.z; a2 = a2 >= 0.f ? a2 : NEG_SLOPE * a2;
        float a3 = xl.w + xr.w + ev.w; a3 = a3 >= 0.f ? a3 : NEG_SLOPE * a3;
        float pp = at.x * a0 + at.y * a1 + at.z * a2 + at.w * a3;
        pp += __shfl_xor(pp, 1);
        pp += __shfl_xor(pp, 2);
        pp += __shfl_xor(pp, 4);
        const float e2 = __expf(pp);
        den += e2;
        acc.x = fmaf(e2, xl.x, acc.x);
        acc.y = fmaf(e2, xl.y, acc.y);
        acc.z = fmaf(e2, xl.z, acc.z);
        acc.w = fmaf(e2, xl.w, acc.w);
    }

    // Normalize per head, then mean over heads (reduce across lane bits 3..5).
    const float inv = 1.f / den;
    float4 v;
    v.x = acc.x * inv; v.y = acc.y * inv; v.z = acc.z * inv; v.w = acc.w * inv;
    v.x += __shfl_xor(v.x, 8);  v.y += __shfl_xor(v.y, 8);
    v.z += __shfl_xor(v.z, 8);  v.w += __shfl_xor(v.w, 8);
    v.x += __shfl_xor(v.x, 16); v.y += __shfl_xor(v.y, 16);
    v.z += __shfl_xor(v.z, 16); v.w += __shfl_xor(v.w, 16);
    v.x += __shfl_xor(v.x, 32); v.y += __shfl_xor(v.y, 32);
    v.z += __shfl_xor(v.z, 32); v.w += __shfl_xor(v.w, 32);
    if (lane < 8) {
        const float4 bs = *(const float4*)(bias + q * 4);
        float4 o;
        o.x = v.x * 0.125f + bs.x;
        o.y = v.y * 0.125f + bs.y;
        o.z = v.z * 0.125f + bs.z;
        o.w = v.w * 0.125f + bs.w;
        *(float4*)(out + (size_t)n * OUT_DIM + q * 4) = o;
    }
}

__global__ void k_copy_rel(const float* __restrict__ relations,
                           float* __restrict__ out_tail) {
    const int i = blockIdx.x * 256 + threadIdx.x;
    if (i < N_REL * EDGE_DIM) out_tail[i] = relations[i];
}

// ---------------------------------------------------------------------------
extern "C" void kernel_launch(void* const* d_in, const int* in_sizes, int n_in,
                              void* d_out, int out_size, void* d_ws, size_t ws_size,
                              hipStream_t stream) {
    const float* x         = (const float*)d_in[0];
    const int*   edge_idx  = (const int*)d_in[1];
    const float* relations = (const float*)d_in[2];
    const int*   rel_idx   = (const int*)d_in[3];
    const float* W_l       = (const float*)d_in[4];
    const float* b_l       = (const float*)d_in[5];
    const float* W_r       = (const float*)d_in[6];
    const float* b_r       = (const float*)d_in[7];
    const float* W_e       = (const float*)d_in[8];
    const float* att       = (const float*)d_in[9];
    const float* bias      = (const float*)d_in[10];

    const int* src_arr = edge_idx;            // edge_index[0, :]
    const int* dst_arr = edge_idx + N_EDGES;  // edge_index[1, :]

    float* out      = (float*)d_out;                 // [N, 32]
    float* out_tail = out + N_NODES * OUT_DIM;       // relations copy

    // Workspace layout (16B-aligned chunks; all counts multiple of 4).
    float* ws        = (float*)d_ws;
    float* x_l       = ws;                                    // 12.8M f
    float* x_r       = x_l + (size_t)N_NODES * HC;            // 12.8M f
    float* self_emb  = x_r + (size_t)N_NODES * HC;            // 12.8M f
    float* rel_emb   = self_emb + (size_t)N_NODES * HC;       // 131072 f
    float* self_attr = rel_emb + (size_t)N_REL * HC;          // 3.2M f
    int*   ibase     = (int*)(self_attr + (size_t)N_NODES * EDGE_DIM);
    int2*  csr       = (int2*)ibase;                          // 400000 int2
    int*   row_ptr   = ibase + 2 * N_EDGES;                   // 50001 (+pad 3)
    int*   incl      = row_ptr + N_NODES + 4;                 // 50000
    int*   deg_i     = incl + N_NODES;                        // 50000 \ zeroed
    int*   cursor    = deg_i + N_NODES;                       // 50000 / together
    int*   partials  = cursor + N_NODES;                      // 256

    hipMemsetAsync(deg_i, 0, 2 * N_NODES * sizeof(int), stream);

    // CSR build.
    k_deg<<<(N_EDGES + 255) / 256, 256, 0, stream>>>(dst_arr, deg_i);
    k_scan_a<<<NB_SCAN, 256, 0, stream>>>(deg_i, incl, partials);
    k_scan_b<<<1, 256, 0, stream>>>(partials);
    k_scan_c<<<NB_SCAN, 256, 0, stream>>>(incl, deg_i, partials, row_ptr);
    k_fill<<<(N_EDGES + 255) / 256, 256, 0, stream>>>(
        src_arr, dst_arr, rel_idx, row_ptr, cursor, csr);

    // Projections.
    const int mt_nodes = (N_NODES + 63) / 64;   // 782
    const int mt_rel   = (N_REL + 63) / 64;     // 8
    // x@W_l and x@W_r share the A tile (dual-output GEMM).
    k_gemm<128, true><<<mt_nodes * 4, 256, 0, stream>>>(
        x, W_l, b_l, W_r, b_r, x_l, x_r, N_NODES);
    k_gemm<64, false><<<mt_rel * 4, 256, 0, stream>>>(
        relations, W_e, nullptr, nullptr, nullptr, rel_emb, nullptr, N_REL);

    k_selfattr<<<(N_NODES * 64 + 255) / 256, 256, 0, stream>>>(
        row_ptr, csr, relations, self_attr);
    k_gemm<64, false><<<mt_nodes * 4, 256, 0, stream>>>(
        self_attr, W_e, nullptr, nullptr, nullptr, self_emb, nullptr, N_NODES);

    // Gather-aggregate + epilogue.
    k_agg<<<(N_NODES * 64 + 255) / 256, 256, 0, stream>>>(
        row_ptr, csr, x_l, x_r, rel_emb, self_emb, att, bias, out);

    k_copy_rel<<<(N_REL * EDGE_DIM + 255) / 256, 256, 0, stream>>>(
        relations, out_tail);
}